// Round 11
// baseline (688.149 us; speedup 1.0000x reference)
//
#include <hip/hip_runtime.h>
#include <hip/hip_bf16.h>

// Problem constants (B=1)
#define CC   448   // channels
#define CGC  64    // key/query channels
#define MMM  7     // m groups
#define HWSZ 4096  // H*W
#define KK2  49    // K*K
#define GPH  32    // geometry-prior hidden

#define GRID_BLOCKS 1024u

typedef __attribute__((ext_vector_type(8))) short   short8;   // 8 bf16 (4 VGPRs)
typedef __attribute__((ext_vector_type(4))) float   f32x4;
typedef __attribute__((ext_vector_type(4))) unsigned short us4;

__device__ __forceinline__ unsigned short f2b(float f) {
    union { __hip_bfloat16 h; unsigned short u; } cv;
    cv.h = __float2bfloat16(f);
    return cv.u;
}

// attn linear-LDS page geometry
#define GLO 196
#define GHI 260
#define XWORDS (GLO + HWSZ + GHI)   // 4552 words
// shared scratch: attn needs (2*4552 + 49)*4 = 36612 B -> 4 blocks/CU (146 KB/160 KB)
#define SMEM_BYTES 36624

__device__ __forceinline__ int win_off_global(int n, bool& ok) {
    int p  = n >> 12;
    int l  = n & 4095;
    int di = (p * 37) >> 8;    // p/7 exact for 0..48
    int dj = p - di * 7;
    int i  = (l >> 6) + di - 3;
    int j  = (l & 63) + dj - 3;
    ok = ((unsigned)i < 64u) && ((unsigned)j < 64u);
    return i * 64 + j;
}

struct P {
    const float *x, *Wk, *bk, *Wq, *bq, *gw1, *gb1, *gw2, *gb2, *Wf, *bfv;
    float *km, *qm, *pre, *out;
    unsigned *bar;   // two single-use barrier counters (zeroed by init kernel)
};

// ---- manual grid barrier: all GRID_BLOCKS co-resident (4 blocks/CU exact) ----
__device__ __forceinline__ void grid_barrier(unsigned* bar, int idx, int tid)
{
    __threadfence();          // publish this thread's prior global writes (device scope)
    __syncthreads();          // whole block done + fenced
    if (tid == 0) {
        __hip_atomic_fetch_add(&bar[idx], 1u, __ATOMIC_ACQ_REL, __HIP_MEMORY_SCOPE_AGENT);
        while (__hip_atomic_load(&bar[idx], __ATOMIC_ACQUIRE, __HIP_MEMORY_SCOPE_AGENT)
               < GRID_BLOCKS)
            __builtin_amdgcn_s_sleep(2);
    }
    __syncthreads();
    __threadfence();          // acquire side for all threads
}

__global__ void init_bar(unsigned* bar) {
    if (threadIdx.x < 2) bar[threadIdx.x] = 0u;
}

// ---------------- Phase 1: fused k+q GEMM, blocks 0..127 -----------------
__device__ __forceinline__ void phase_kq(const P& p, unsigned char* smem, int bid, int tid)
{
    unsigned short* As = (unsigned short*)smem;           // 8 KB [kg4][m128][j8]
    unsigned short* Bs = (unsigned short*)(smem + 8192);  // 2 KB [kg4][n32][j8]

    const int nT   = bid * 32;
    const int lane = tid & 63;
    const int wid  = tid >> 6;
    const int wm   = wid * 32;
    const int l15  = lane & 15;
    const int l4   = lane >> 4;

    const int ar  = tid >> 3;
    const int ak  = tid & 7;
    const int bkr = tid >> 3;
    const int bn4 = tid & 7;

    f32x4 acc[2][2];
    #pragma unroll
    for (int i = 0; i < 2; ++i)
        #pragma unroll
        for (int j = 0; j < 2; ++j)
            acc[i][j] = (f32x4){0.f, 0.f, 0.f, 0.f};

    float4 a0 = *(const float4*)(p.Wk + (size_t)ar * CC + ak * 4);
    float4 a1 = *(const float4*)(p.Wk + (size_t)(ar + 32) * CC + ak * 4);
    float4 a2 = *(const float4*)(p.Wq + (size_t)ar * CC + ak * 4);
    float4 a3 = *(const float4*)(p.Wq + (size_t)(ar + 32) * CC + ak * 4);
    float4 b0 = *(const float4*)(p.x + (size_t)bkr * HWSZ + nT + bn4 * 4);

    for (int kt = 0; kt < 14; ++kt) {
        {
            int kg = ak >> 1, jo = (ak & 1) * 4;
            us4 w;
            w = (us4){ f2b(a0.x), f2b(a0.y), f2b(a0.z), f2b(a0.w) };
            *(us4*)&As[kg * 1024 + (ar +  0) * 8 + jo] = w;
            w = (us4){ f2b(a1.x), f2b(a1.y), f2b(a1.z), f2b(a1.w) };
            *(us4*)&As[kg * 1024 + (ar + 32) * 8 + jo] = w;
            w = (us4){ f2b(a2.x), f2b(a2.y), f2b(a2.z), f2b(a2.w) };
            *(us4*)&As[kg * 1024 + (ar + 64) * 8 + jo] = w;
            w = (us4){ f2b(a3.x), f2b(a3.y), f2b(a3.z), f2b(a3.w) };
            *(us4*)&As[kg * 1024 + (ar + 96) * 8 + jo] = w;
            int base = (bkr >> 3) * 256 + bn4 * 32 + (bkr & 7);
            Bs[base]      = f2b(b0.x);
            Bs[base + 8]  = f2b(b0.y);
            Bs[base + 16] = f2b(b0.z);
            Bs[base + 24] = f2b(b0.w);
        }
        __syncthreads();
        if (kt < 13) {  // prefetch after barrier: drain lands at next barrier
            int ko = (kt + 1) * 32;
            a0 = *(const float4*)(p.Wk + (size_t)ar * CC + ko + ak * 4);
            a1 = *(const float4*)(p.Wk + (size_t)(ar + 32) * CC + ko + ak * 4);
            a2 = *(const float4*)(p.Wq + (size_t)ar * CC + ko + ak * 4);
            a3 = *(const float4*)(p.Wq + (size_t)(ar + 32) * CC + ko + ak * 4);
            b0 = *(const float4*)(p.x + (size_t)(ko + bkr) * HWSZ + nT + bn4 * 4);
        }
        short8 fa0 = *(short8*)&As[l4 * 1024 + (wm + l15) * 8];
        short8 fa1 = *(short8*)&As[l4 * 1024 + (wm + 16 + l15) * 8];
        short8 fb0 = *(short8*)&Bs[l4 * 256 + l15 * 8];
        short8 fb1 = *(short8*)&Bs[l4 * 256 + (16 + l15) * 8];
        acc[0][0] = __builtin_amdgcn_mfma_f32_16x16x32_bf16(fa0, fb0, acc[0][0], 0, 0, 0);
        acc[0][1] = __builtin_amdgcn_mfma_f32_16x16x32_bf16(fa0, fb1, acc[0][1], 0, 0, 0);
        acc[1][0] = __builtin_amdgcn_mfma_f32_16x16x32_bf16(fa1, fb0, acc[1][0], 0, 0, 0);
        acc[1][1] = __builtin_amdgcn_mfma_f32_16x16x32_bf16(fa1, fb1, acc[1][1], 0, 0, 0);
        __syncthreads();
    }
    const bool isK = (wid < 2);
    float*       Cd   = isK ? p.km : p.qm;
    const float* bias = isK ? p.bk : p.bq;
    const int rbase = (wm & 63);
    #pragma unroll
    for (int wm2 = 0; wm2 < 2; ++wm2)
        #pragma unroll
        for (int wn2 = 0; wn2 < 2; ++wn2)
            #pragma unroll
            for (int r = 0; r < 4; ++r) {
                int row = rbase + wm2 * 16 + l4 * 4 + r;
                int col = nT + wn2 * 16 + l15;
                Cd[(size_t)row * HWSZ + col] = acc[wm2][wn2][r] + bias[row];
            }
}

// ---------------- Phase 2: attention, all 1024 blocks --------------------
__device__ __forceinline__ void phase_attn(const P& p, unsigned char* smem, int bid, int tid)
{
    float* klin  = (float*)smem;           // 4552
    float* xlin  = klin + XWORDS;          // 4552
    float* gpk_s = xlin + XWORDS;          // 49

    const int g  = bid >> 4;
    const int lp = (bid & 15) * 256 + tid;

    if (tid < 114) {
        float4 z = {0.f, 0.f, 0.f, 0.f};
        int w = (tid < 49) ? tid * 4 : (GLO + HWSZ + (tid - 49) * 4);
        *(float4*)&klin[w] = z;
        *(float4*)&xlin[w] = z;
    }
    {
        const float4* km4 = (const float4*)(p.km + (size_t)g * HWSZ);
        #pragma unroll
        for (int i = 0; i < 4; ++i) {
            int idx = tid + i * 256;
            *(float4*)&klin[GLO + idx * 4] = km4[idx];
        }
    }
    if (tid < KK2) {
        int di = tid / 7, dj = tid - di * 7;
        float xp = (float)(dj - 3);
        float yp = (float)(3 - di);
        float acc = p.gb2[g];
        #pragma unroll
        for (int j = 0; j < GPH; ++j) {
            float h = p.gw1[j * 2 + 0] * xp + p.gw1[j * 2 + 1] * yp + p.gb1[j];
            h = fmaxf(h, 0.f);
            acc = fmaf(p.gw2[g * GPH + j], h, acc);
        }
        gpk_s[tid] = acc;
    }

    float qc;
    { bool ok; int o = win_off_global(lp * KK2 + 24, ok); qc = ok ? p.qm[(size_t)g * HWSZ + o] : 0.f; }

    const int n0 = lp * KK2;
    const int p0 = n0 >> 12;
    const int l0 = n0 & 4095;
    const int ts = ((p0 + 1) << 12) - n0;
    const int di0 = (p0 * 37) >> 8, dj0 = p0 - di0 * 7;
    const int p1  = p0 + 1;
    const int di1 = (p1 * 37) >> 8, dj1 = p1 - di1 * 7;
    const int djm3_0 = dj0 - 3, djm3_1 = dj1 - 3;
    const int B0 = GLO + l0 + (di0 - 3) * 64 + djm3_0;
    const int B1 = GLO + l0 - 4096 + (di1 - 3) * 64 + djm3_1;

    float4 xr0, xr1, xr2, xr3;
    {
        const float4* xg4 = (const float4*)(p.x + (size_t)g * HWSZ);
        xr0 = xg4[tid]; xr1 = xg4[tid + 256]; xr2 = xg4[tid + 512]; xr3 = xg4[tid + 768];
    }
    __syncthreads();

    float a[KK2];
    float mx = -1e30f;
    #pragma unroll
    for (int t = 0; t < KK2; ++t) {
        bool s1 = (t >= ts);
        int base = s1 ? B1 : B0;
        float kv = klin[base + t];
        int jj = ((l0 + t) & 63) + (s1 ? djm3_1 : djm3_0);
        kv = ((unsigned)jj < 64u) ? kv : 0.f;
        float av = fmaf(kv, qc, gpk_s[t]);
        a[t] = av;
        mx = fmaxf(mx, av);
    }
    float d = 0.f;
    #pragma unroll
    for (int t = 0; t < KK2; ++t) {
        float e = __expf(a[t] - mx);
        d += e;                                  // padded taps count in denominator
        bool s1 = (t >= ts);
        int jj = ((l0 + t) & 63) + (s1 ? djm3_1 : djm3_0);
        a[t] = ((unsigned)jj < 64u) ? e : 0.f;
    }
    const float inv = 1.f / d;

    #pragma unroll 1
    for (int m = 0; m < MMM; ++m) {
        __syncthreads();
        *(float4*)&xlin[GLO + tid * 4]          = xr0;
        *(float4*)&xlin[GLO + (tid + 256) * 4]  = xr1;
        *(float4*)&xlin[GLO + (tid + 512) * 4]  = xr2;
        *(float4*)&xlin[GLO + (tid + 768) * 4]  = xr3;
        if (m < MMM - 1) {
            const float4* xg4 = (const float4*)(p.x + (size_t)((m + 1) * CGC + g) * HWSZ);
            xr0 = xg4[tid]; xr1 = xg4[tid + 256]; xr2 = xg4[tid + 512]; xr3 = xg4[tid + 768];
        }
        __syncthreads();
        float acc = 0.f;
        #pragma unroll
        for (int t = 0; t < KK2; ++t) {
            int base = (t >= ts) ? B1 : B0;
            acc = fmaf(a[t], xlin[base + t], acc);
        }
        p.pre[(size_t)(m * CGC + g) * HWSZ + lp] = acc * inv;
    }
}

// ---------------- Phase 3: fconv GEMM, blocks 0..895 ---------------------
__device__ __forceinline__ void phase_fconv(const P& p, unsigned char* smem, int bid, int tid)
{
    unsigned short* As = (unsigned short*)smem;           // 4 KB [kg4][m64][j8]
    unsigned short* Bs = (unsigned short*)(smem + 4096);  // 2 KB [kg4][n32][j8]

    const int nT   = (bid & 127) * 32;
    const int oT   = (bid >> 7) * 64;
    const int lane = tid & 63;
    const int wid  = tid >> 6;
    const int l15  = lane & 15;
    const int l4   = lane >> 4;

    const int ar  = tid >> 3;
    const int ak  = tid & 7;
    const int bkr = tid >> 3;
    const int bn4 = tid & 7;

    const float* __restrict__ A = p.Wf + (size_t)oT * CC;

    f32x4 acc[2];
    acc[0] = (f32x4){0.f, 0.f, 0.f, 0.f};
    acc[1] = (f32x4){0.f, 0.f, 0.f, 0.f};

    float4 a0 = *(const float4*)(A + (size_t)ar * CC + ak * 4);
    float4 a1 = *(const float4*)(A + (size_t)(ar + 32) * CC + ak * 4);
    float4 b0 = *(const float4*)(p.pre + (size_t)bkr * HWSZ + nT + bn4 * 4);

    for (int kt = 0; kt < 14; ++kt) {
        {
            int kg = ak >> 1, jo = (ak & 1) * 4;
            us4 w;
            w = (us4){ f2b(a0.x), f2b(a0.y), f2b(a0.z), f2b(a0.w) };
            *(us4*)&As[kg * 512 + (ar +  0) * 8 + jo] = w;
            w = (us4){ f2b(a1.x), f2b(a1.y), f2b(a1.z), f2b(a1.w) };
            *(us4*)&As[kg * 512 + (ar + 32) * 8 + jo] = w;
            int base = (bkr >> 3) * 256 + bn4 * 32 + (bkr & 7);
            Bs[base]      = f2b(b0.x);
            Bs[base + 8]  = f2b(b0.y);
            Bs[base + 16] = f2b(b0.z);
            Bs[base + 24] = f2b(b0.w);
        }
        __syncthreads();
        if (kt < 13) {
            int ko = (kt + 1) * 32;
            a0 = *(const float4*)(A + (size_t)ar * CC + ko + ak * 4);
            a1 = *(const float4*)(A + (size_t)(ar + 32) * CC + ko + ak * 4);
            b0 = *(const float4*)(p.pre + (size_t)(ko + bkr) * HWSZ + nT + bn4 * 4);
        }
        short8 fa  = *(short8*)&As[l4 * 512 + (wid * 16 + l15) * 8];
        short8 fb0 = *(short8*)&Bs[l4 * 256 + l15 * 8];
        short8 fb1 = *(short8*)&Bs[l4 * 256 + (16 + l15) * 8];
        acc[0] = __builtin_amdgcn_mfma_f32_16x16x32_bf16(fa, fb0, acc[0], 0, 0, 0);
        acc[1] = __builtin_amdgcn_mfma_f32_16x16x32_bf16(fa, fb1, acc[1], 0, 0, 0);
        __syncthreads();
    }
    #pragma unroll
    for (int wn2 = 0; wn2 < 2; ++wn2)
        #pragma unroll
        for (int r = 0; r < 4; ++r) {
            int row = oT + wid * 16 + l4 * 4 + r;
            int col = nT + wn2 * 16 + l15;
            p.out[(size_t)row * HWSZ + col] = acc[wn2][r] + p.bfv[row];
        }
}

// ---------------- Fused kernel with manual grid barriers -----------------
__global__ void __launch_bounds__(256, 4) fused_all(P p)
{
    __shared__ __align__(16) unsigned char smem[SMEM_BYTES];
    const int bid = blockIdx.x;
    const int tid = threadIdx.x;

    if (bid < 128) phase_kq(p, smem, bid, tid);
    grid_barrier(p.bar, 0, tid);               // km/qm visible device-wide
    phase_attn(p, smem, bid, tid);
    grid_barrier(p.bar, 1, tid);               // pre visible device-wide
    if (bid < 896) phase_fconv(p, smem, bid, tid);
}

extern "C" void kernel_launch(void* const* d_in, const int* in_sizes, int n_in,
                              void* d_out, int out_size, void* d_ws, size_t ws_size,
                              hipStream_t stream) {
    P hp;
    hp.x   = (const float*)d_in[0];
    hp.Wk  = (const float*)d_in[1];
    hp.bk  = (const float*)d_in[2];
    hp.Wq  = (const float*)d_in[3];
    hp.bq  = (const float*)d_in[4];
    hp.gw1 = (const float*)d_in[5];
    hp.gb1 = (const float*)d_in[6];
    hp.gw2 = (const float*)d_in[7];
    hp.gb2 = (const float*)d_in[8];
    hp.Wf  = (const float*)d_in[9];
    hp.bfv = (const float*)d_in[10];
    hp.out = (float*)d_out;

    hp.km  = (float*)d_ws;                 // 64*4096
    hp.qm  = hp.km + CGC * HWSZ;           // 64*4096
    hp.pre = hp.qm + CGC * HWSZ;           // 448*4096
    hp.bar = (unsigned*)(hp.pre + (size_t)CC * HWSZ);   // 2 counters

    init_bar <<<1, 64, 0, stream>>>(hp.bar);
    fused_all<<<dim3(GRID_BLOCKS), dim3(256), 0, stream>>>(hp);
}

// Round 12
// 114.917 us; speedup vs baseline: 5.9882x; 5.9882x over previous
//
#include <hip/hip_runtime.h>
#include <hip/hip_bf16.h>

// Problem constants (B=1)
#define CC   448   // channels
#define CGC  64    // key/query channels
#define MMM  7     // m groups
#define HWSZ 4096  // H*W
#define KK2  49    // K*K
#define GPH  32    // geometry-prior hidden

typedef __attribute__((ext_vector_type(8))) short   short8;   // 8 bf16 (4 VGPRs)
typedef __attribute__((ext_vector_type(4))) float   f32x4;
typedef __attribute__((ext_vector_type(4))) unsigned short us4;

__device__ __forceinline__ unsigned short f2b(float f) {
    union { __hip_bfloat16 h; unsigned short u; } cv;
    cv.h = __float2bfloat16(f);
    return cv.u;
}

// ---------------- Kernel 1: fused k+q GEMM, 128x16 tiles, 256 blocks -----
// C[128,4096] = [Wk;Wq] @ x. 256 blocks = 1 block/CU (was 0.5 -> half chip idle).
__global__ __launch_bounds__(256) void kq_mfma(
    const float* __restrict__ x,
    const float* __restrict__ Wk, const float* __restrict__ bk,
    const float* __restrict__ Wq, const float* __restrict__ bq,
    float* __restrict__ km, float* __restrict__ qm)
{
    __shared__ unsigned short As[4096];   // 8 KB [kg4][m128][j8]
    __shared__ unsigned short Bs[512];    // 1 KB [kg4][n16][j8]

    const int tid  = threadIdx.x;
    const int nT   = blockIdx.x * 16;
    const int lane = tid & 63;
    const int wid  = tid >> 6;
    const int wm   = wid * 32;
    const int l15  = lane & 15;
    const int l4   = lane >> 4;

    const int ar  = tid >> 3;         // 0..31: A row within rep
    const int ak  = tid & 7;          // which float4 of the 32-k chunk
    const int bkr = tid >> 3;         // 0..31: B k-row
    const int bn2 = tid & 7;          // 0..7: B float2 col group (16 cols)

    f32x4 acc[2];
    acc[0] = (f32x4){0.f, 0.f, 0.f, 0.f};
    acc[1] = (f32x4){0.f, 0.f, 0.f, 0.f};

    float4 a0 = *(const float4*)(Wk + (size_t)ar * CC + ak * 4);
    float4 a1 = *(const float4*)(Wk + (size_t)(ar + 32) * CC + ak * 4);
    float4 a2 = *(const float4*)(Wq + (size_t)ar * CC + ak * 4);
    float4 a3 = *(const float4*)(Wq + (size_t)(ar + 32) * CC + ak * 4);
    float2 b0 = *(const float2*)(x + (size_t)bkr * HWSZ + nT + bn2 * 2);

    for (int kt = 0; kt < 14; ++kt) {
        {
            int kg = ak >> 1, jo = (ak & 1) * 4;
            us4 w;
            w = (us4){ f2b(a0.x), f2b(a0.y), f2b(a0.z), f2b(a0.w) };
            *(us4*)&As[kg * 1024 + (ar +  0) * 8 + jo] = w;
            w = (us4){ f2b(a1.x), f2b(a1.y), f2b(a1.z), f2b(a1.w) };
            *(us4*)&As[kg * 1024 + (ar + 32) * 8 + jo] = w;
            w = (us4){ f2b(a2.x), f2b(a2.y), f2b(a2.z), f2b(a2.w) };
            *(us4*)&As[kg * 1024 + (ar + 64) * 8 + jo] = w;
            w = (us4){ f2b(a3.x), f2b(a3.y), f2b(a3.z), f2b(a3.w) };
            *(us4*)&As[kg * 1024 + (ar + 96) * 8 + jo] = w;
            int base = (bkr >> 3) * 128 + bn2 * 16 + (bkr & 7);
            Bs[base]     = f2b(b0.x);
            Bs[base + 8] = f2b(b0.y);
        }
        __syncthreads();
        if (kt < 13) {  // drain lands at NEXT barrier, overlapped by MFMA
            int ko = (kt + 1) * 32;
            a0 = *(const float4*)(Wk + (size_t)ar * CC + ko + ak * 4);
            a1 = *(const float4*)(Wk + (size_t)(ar + 32) * CC + ko + ak * 4);
            a2 = *(const float4*)(Wq + (size_t)ar * CC + ko + ak * 4);
            a3 = *(const float4*)(Wq + (size_t)(ar + 32) * CC + ko + ak * 4);
            b0 = *(const float2*)(x + (size_t)(ko + bkr) * HWSZ + nT + bn2 * 2);
        }
        short8 fa0 = *(short8*)&As[l4 * 1024 + (wm + l15) * 8];
        short8 fa1 = *(short8*)&As[l4 * 1024 + (wm + 16 + l15) * 8];
        short8 fb0 = *(short8*)&Bs[l4 * 128 + l15 * 8];
        acc[0] = __builtin_amdgcn_mfma_f32_16x16x32_bf16(fa0, fb0, acc[0], 0, 0, 0);
        acc[1] = __builtin_amdgcn_mfma_f32_16x16x32_bf16(fa1, fb0, acc[1], 0, 0, 0);
        __syncthreads();
    }
    const bool isK = (wid < 2);
    float*       Cd   = isK ? km : qm;
    const float* bias = isK ? bk : bq;
    const int rbase = wm & 63;
    #pragma unroll
    for (int wm2 = 0; wm2 < 2; ++wm2)
        #pragma unroll
        for (int r = 0; r < 4; ++r) {
            int row = rbase + wm2 * 16 + l4 * 4 + r;
            int col = nT + l15;
            Cd[(size_t)row * HWSZ + col] = acc[wm2][r] + bias[row];
        }
}

// ---------------- Kernel 3: fconv GEMM, 64x32 tiles, 896 blocks (R7) -----
__global__ __launch_bounds__(256) void fconv_mfma(
    const float* __restrict__ pre,
    const float* __restrict__ Wf, const float* __restrict__ bfv,
    float* __restrict__ out)
{
    __shared__ unsigned short As[2048];   // 4 KB [kg4][m64][j8]
    __shared__ unsigned short Bs[1024];   // 2 KB [kg4][n32][j8]

    const int tid  = threadIdx.x;
    const int nT   = blockIdx.x * 32;
    const int oT   = blockIdx.y * 64;
    const int lane = tid & 63;
    const int wid  = tid >> 6;
    const int l15  = lane & 15;
    const int l4   = lane >> 4;

    const int ar  = tid >> 3;
    const int ak  = tid & 7;
    const int bkr = tid >> 3;
    const int bn4 = tid & 7;

    const float* __restrict__ A = Wf + (size_t)oT * CC;

    f32x4 acc[2];
    acc[0] = (f32x4){0.f, 0.f, 0.f, 0.f};
    acc[1] = (f32x4){0.f, 0.f, 0.f, 0.f};

    float4 a0 = *(const float4*)(A + (size_t)ar * CC + ak * 4);
    float4 a1 = *(const float4*)(A + (size_t)(ar + 32) * CC + ak * 4);
    float4 b0 = *(const float4*)(pre + (size_t)bkr * HWSZ + nT + bn4 * 4);

    for (int kt = 0; kt < 14; ++kt) {
        {
            int kg = ak >> 1, jo = (ak & 1) * 4;
            us4 w;
            w = (us4){ f2b(a0.x), f2b(a0.y), f2b(a0.z), f2b(a0.w) };
            *(us4*)&As[kg * 512 + (ar +  0) * 8 + jo] = w;
            w = (us4){ f2b(a1.x), f2b(a1.y), f2b(a1.z), f2b(a1.w) };
            *(us4*)&As[kg * 512 + (ar + 32) * 8 + jo] = w;
            int base = (bkr >> 3) * 256 + bn4 * 32 + (bkr & 7);
            Bs[base]      = f2b(b0.x);
            Bs[base + 8]  = f2b(b0.y);
            Bs[base + 16] = f2b(b0.z);
            Bs[base + 24] = f2b(b0.w);
        }
        __syncthreads();
        if (kt < 13) {
            int ko = (kt + 1) * 32;
            a0 = *(const float4*)(A + (size_t)ar * CC + ko + ak * 4);
            a1 = *(const float4*)(A + (size_t)(ar + 32) * CC + ko + ak * 4);
            b0 = *(const float4*)(pre + (size_t)(ko + bkr) * HWSZ + nT + bn4 * 4);
        }
        short8 fa  = *(short8*)&As[l4 * 512 + (wid * 16 + l15) * 8];
        short8 fb0 = *(short8*)&Bs[l4 * 256 + l15 * 8];
        short8 fb1 = *(short8*)&Bs[l4 * 256 + (16 + l15) * 8];
        acc[0] = __builtin_amdgcn_mfma_f32_16x16x32_bf16(fa, fb0, acc[0], 0, 0, 0);
        acc[1] = __builtin_amdgcn_mfma_f32_16x16x32_bf16(fa, fb1, acc[1], 0, 0, 0);
        __syncthreads();
    }
    #pragma unroll
    for (int wn2 = 0; wn2 < 2; ++wn2)
        #pragma unroll
        for (int r = 0; r < 4; ++r) {
            int row = oT + wid * 16 + l4 * 4 + r;
            int col = nT + wn2 * 16 + l15;
            out[(size_t)row * HWSZ + col] = acc[wn2][r] + bfv[row];
        }
}

// ---------------- Kernel 2: attention, 512-thr blocks (half staging) -----
#define GLO 196
#define GHI 260
#define XWORDS (GLO + HWSZ + GHI)   // 4552 words

__device__ __forceinline__ int win_off_global(int n, bool& ok) {
    int p  = n >> 12;
    int l  = n & 4095;
    int di = (p * 37) >> 8;    // p/7 exact for 0..48
    int dj = p - di * 7;
    int i  = (l >> 6) + di - 3;
    int j  = (l & 63) + dj - 3;
    ok = ((unsigned)i < 64u) && ((unsigned)j < 64u);
    return i * 64 + j;
}

// grid (8, 64): 512 blocks = 2/CU, 8 waves/block = 16 waves/CU. Each block
// covers 512 lp -> x/km staging traffic halves vs 256-thr blocks.
// __launch_bounds__(512,4): VGPR cap 128 (~100 needed, no spill).
__global__ __launch_bounds__(512, 4) void attn_kernel(
    const float* __restrict__ km, const float* __restrict__ qm,
    const float* __restrict__ x,
    const float* __restrict__ gw1, const float* __restrict__ gb1,
    const float* __restrict__ gw2, const float* __restrict__ gb2,
    float* __restrict__ pre)
{
    __shared__ float klin[XWORDS];
    __shared__ float xlin[XWORDS];
    __shared__ float gpk_s[KK2];
    const int tid = threadIdx.x;
    const int g   = blockIdx.y;
    const int lp  = blockIdx.x * 512 + tid;

    // zero guard bands: lo 49 float4, hi 65 float4 each
    if (tid < 114) {
        float4 z = {0.f, 0.f, 0.f, 0.f};
        int w = (tid < 49) ? tid * 4 : (GLO + HWSZ + (tid - 49) * 4);
        *(float4*)&klin[w] = z;
        *(float4*)&xlin[w] = z;
    }
    // stage km page: 1024 float4 over 512 threads
    {
        const float4* km4 = (const float4*)(km + (size_t)g * HWSZ);
        *(float4*)&klin[GLO + tid * 4]         = km4[tid];
        *(float4*)&klin[GLO + (tid + 512) * 4] = km4[tid + 512];
    }
    // fused geometry prior: row g (49 values)
    if (tid < KK2) {
        int di = tid / 7, dj = tid - di * 7;
        float xp = (float)(dj - 3);
        float yp = (float)(3 - di);
        float acc = gb2[g];
        #pragma unroll
        for (int j = 0; j < GPH; ++j) {
            float h = gw1[j * 2 + 0] * xp + gw1[j * 2 + 1] * yp + gb1[j];
            h = fmaxf(h, 0.f);
            acc = fmaf(gw2[g * GPH + j], h, acc);
        }
        gpk_s[tid] = acc;
    }

    // q center
    float qc;
    { bool ok; int o = win_off_global(lp * KK2 + 24, ok); qc = ok ? qm[(size_t)g * HWSZ + o] : 0.f; }

    // per-thread segment constants (taps contiguous in <=2 segments)
    const int n0 = lp * KK2;
    const int p0 = n0 >> 12;
    const int l0 = n0 & 4095;
    const int ts = ((p0 + 1) << 12) - n0;
    const int di0 = (p0 * 37) >> 8, dj0 = p0 - di0 * 7;
    const int p1  = p0 + 1;
    const int di1 = (p1 * 37) >> 8, dj1 = p1 - di1 * 7;
    const int djm3_0 = dj0 - 3, djm3_1 = dj1 - 3;
    const int B0 = GLO + l0 + (di0 - 3) * 64 + djm3_0;
    const int B1 = GLO + l0 - 4096 + (di1 - 3) * 64 + djm3_1;

    // prefetch m=0 x page (2 float4/thread)
    float4 xr0, xr1;
    {
        const float4* xg4 = (const float4*)(x + (size_t)g * HWSZ);
        xr0 = xg4[tid]; xr1 = xg4[tid + 512];
    }
    __syncthreads();   // klin/guards/gpk staged

    // Phase A: logits
    float a[KK2];
    float mx = -1e30f;
    #pragma unroll
    for (int t = 0; t < KK2; ++t) {
        bool s1 = (t >= ts);
        int base = s1 ? B1 : B0;
        float kv = klin[base + t];
        int jj = ((l0 + t) & 63) + (s1 ? djm3_1 : djm3_0);
        kv = ((unsigned)jj < 64u) ? kv : 0.f;
        float av = fmaf(kv, qc, gpk_s[t]);
        a[t] = av;
        mx = fmaxf(mx, av);
    }
    float d = 0.f;
    #pragma unroll
    for (int t = 0; t < KK2; ++t) {
        float e = __expf(a[t] - mx);
        d += e;                                  // padded taps count in denominator
        bool s1 = (t >= ts);
        int jj = ((l0 + t) & 63) + (s1 ? djm3_1 : djm3_0);
        a[t] = ((unsigned)jj < 64u) ? e : 0.f;
    }
    const float inv = 1.f / d;

    // Phase B: per m, write staged page, prefetch next AFTER ready-barrier
    // (its vmcnt drain lands at next iter's first barrier, overlapped by taps)
    #pragma unroll 1
    for (int m = 0; m < MMM; ++m) {
        __syncthreads();   // prior readers of xlin done (+ prefetch drained)
        *(float4*)&xlin[GLO + tid * 4]         = xr0;
        *(float4*)&xlin[GLO + (tid + 512) * 4] = xr1;
        __syncthreads();   // xlin ready
        if (m < MMM - 1) {
            const float4* xg4 = (const float4*)(x + (size_t)((m + 1) * CGC + g) * HWSZ);
            xr0 = xg4[tid]; xr1 = xg4[tid + 512];
        }
        float acc = 0.f;
        #pragma unroll
        for (int t = 0; t < KK2; ++t) {
            int base = (t >= ts) ? B1 : B0;
            acc = fmaf(a[t], xlin[base + t], acc);
        }
        pre[(size_t)(m * CGC + g) * HWSZ + lp] = acc * inv;
    }
}

extern "C" void kernel_launch(void* const* d_in, const int* in_sizes, int n_in,
                              void* d_out, int out_size, void* d_ws, size_t ws_size,
                              hipStream_t stream) {
    const float* x   = (const float*)d_in[0];
    const float* Wk  = (const float*)d_in[1];
    const float* bk  = (const float*)d_in[2];
    const float* Wq  = (const float*)d_in[3];
    const float* bq  = (const float*)d_in[4];
    const float* gw1 = (const float*)d_in[5];
    const float* gb1 = (const float*)d_in[6];
    const float* gw2 = (const float*)d_in[7];
    const float* gb2 = (const float*)d_in[8];
    const float* Wf  = (const float*)d_in[9];
    const float* bfv = (const float*)d_in[10];
    float* out = (float*)d_out;

    float* km  = (float*)d_ws;             // 64*4096
    float* qm  = km + CGC * HWSZ;          // 64*4096
    float* pre = qm + CGC * HWSZ;          // 448*4096

    kq_mfma    <<<dim3(256),    256, 0, stream>>>(x, Wk, bk, Wq, bq, km, qm);
    attn_kernel<<<dim3(8, CGC), 512, 0, stream>>>(km, qm, x, gw1, gb1, gw2, gb2, pre);
    fconv_mfma <<<dim3(128, 7), 256, 0, stream>>>(pre, Wf, bfv, out);
}